// Round 14
// baseline (1246.355 us; speedup 1.0000x reference)
//
#include <hip/hip_runtime.h>
#include <math.h>

// Problem constants
#define BB 64
#define LL 24
#define DD 512
#define GG 2560        // 5*H
#define NSTEP 23       // LL-1
#define NTILES 160     // stepB n-tiles: 5120/32, full-K per tile
#define FUSED_BLOCKS 224

__device__ __forceinline__ float sigm(float x) { return 1.0f / (1.0f + __expf(-x)); }

// ---------------------------------------------------------------------------
// sc1 helpers (agent-scope relaxed — no cache maintenance; R5/R6 lesson)
// ---------------------------------------------------------------------------
__device__ __forceinline__ void stf2(float* p, float a, float b) {
    union { float f[2]; unsigned long long u; } x;
    x.f[0] = a; x.f[1] = b;
    __hip_atomic_store((unsigned long long*)p, x.u, __ATOMIC_RELAXED, __HIP_MEMORY_SCOPE_AGENT);
}
__device__ __forceinline__ float2 ldf2(const float* p) {
    union { float f[2]; unsigned long long u; } x;
    x.u = __hip_atomic_load((unsigned long long*)p, __ATOMIC_RELAXED, __HIP_MEMORY_SCOPE_AGENT);
    return make_float2(x.f[0], x.f[1]);
}
__device__ __forceinline__ int ldi(const int* p) {
    return __hip_atomic_load((int*)p, __ATOMIC_RELAXED, __HIP_MEMORY_SCOPE_AGENT);
}
__device__ __forceinline__ void drain_stores() {
    asm volatile("s_waitcnt vmcnt(0)" ::: "memory");
}

__global__ void init_k(int* __restrict__ bar) {
    for (int idx = threadIdx.x; idx < NSTEP * 64; idx += 256) bar[idx] = 0;
}

// ---------------------------------------------------------------------------
// AB0 GEMM: 128x128 tile, 8x8 microtile, register-prefetch pipeline (the
// stepB-proven structure: stage->sync->issue next loads->compute->sync).
// ---------------------------------------------------------------------------
__global__ __launch_bounds__(256) void gemm_big(const float* __restrict__ A,
                                                const float* __restrict__ Wt,
                                                float* __restrict__ O0,
                                                float* __restrict__ O1) {
    __shared__ float As[16][132];
    __shared__ float Bs[16][132];
    const int tid = threadIdx.x;
    const int n0 = blockIdx.x * 128;
    const int m0 = blockIdx.y * 128;
    const int tn = tid & 15;
    const int tm = tid >> 4;
    const int r0 = tid >> 2, c4 = tid & 3;   // staging role: rows r0, r0+64

    const float* a0p = A + (size_t)(m0 + r0) * DD + c4 * 4;
    const float* a1p = A + (size_t)(m0 + r0 + 64) * DD + c4 * 4;
    const float* w0p;
    const float* w1p;
    {
        int n = n0 + r0;
        w0p = (n < GG) ? (Wt + (size_t)n * (2 * DD) + c4 * 4)
                       : (Wt + (size_t)(n - GG) * (2 * DD) + DD + c4 * 4);
        n = n0 + r0 + 64;
        w1p = (n < GG) ? (Wt + (size_t)n * (2 * DD) + c4 * 4)
                       : (Wt + (size_t)(n - GG) * (2 * DD) + DD + c4 * 4);
    }

    float acc[8][8];
#pragma unroll
    for (int y = 0; y < 8; ++y)
#pragma unroll
        for (int x = 0; x < 8; ++x) acc[y][x] = 0.f;

    float4 pa0 = *(const float4*)a0p;
    float4 pa1 = *(const float4*)a1p;
    float4 pw0 = *(const float4*)w0p;
    float4 pw1 = *(const float4*)w1p;

#pragma unroll 1
    for (int kt = 0; kt < 512; kt += 16) {
        As[c4 * 4 + 0][r0] = pa0.x; As[c4 * 4 + 1][r0] = pa0.y;
        As[c4 * 4 + 2][r0] = pa0.z; As[c4 * 4 + 3][r0] = pa0.w;
        As[c4 * 4 + 0][r0 + 64] = pa1.x; As[c4 * 4 + 1][r0 + 64] = pa1.y;
        As[c4 * 4 + 2][r0 + 64] = pa1.z; As[c4 * 4 + 3][r0 + 64] = pa1.w;
        Bs[c4 * 4 + 0][r0] = pw0.x; Bs[c4 * 4 + 1][r0] = pw0.y;
        Bs[c4 * 4 + 2][r0] = pw0.z; Bs[c4 * 4 + 3][r0] = pw0.w;
        Bs[c4 * 4 + 0][r0 + 64] = pw1.x; Bs[c4 * 4 + 1][r0 + 64] = pw1.y;
        Bs[c4 * 4 + 2][r0 + 64] = pw1.z; Bs[c4 * 4 + 3][r0 + 64] = pw1.w;
        __syncthreads();
        if (kt + 16 < 512) {  // prefetch next k-tile during compute
            pa0 = *(const float4*)(a0p + kt + 16);
            pa1 = *(const float4*)(a1p + kt + 16);
            pw0 = *(const float4*)(w0p + kt + 16);
            pw1 = *(const float4*)(w1p + kt + 16);
        }
#pragma unroll
        for (int k = 0; k < 16; ++k) {
            float4 a0 = *(const float4*)&As[k][tm * 8];
            float4 a1 = *(const float4*)&As[k][tm * 8 + 4];
            float4 b0 = *(const float4*)&Bs[k][tn * 4];
            float4 b1 = *(const float4*)&Bs[k][64 + tn * 4];
            float av[8] = {a0.x, a0.y, a0.z, a0.w, a1.x, a1.y, a1.z, a1.w};
            float bv[8] = {b0.x, b0.y, b0.z, b0.w, b1.x, b1.y, b1.z, b1.w};
#pragma unroll
            for (int y = 0; y < 8; ++y)
#pragma unroll
                for (int x = 0; x < 8; ++x) acc[y][x] += av[y] * bv[x];
        }
        __syncthreads();
    }

#pragma unroll
    for (int y = 0; y < 8; ++y) {
        const int m = m0 + tm * 8 + y;
#pragma unroll
        for (int g = 0; g < 2; ++g) {
            int n = n0 + g * 64 + tn * 4;
            float4 v;
            v.x = acc[y][g * 4 + 0];
            v.y = acc[y][g * 4 + 1];
            v.z = acc[y][g * 4 + 2];
            v.w = acc[y][g * 4 + 3];
            float* dst = (n < GG) ? (O0 + (size_t)m * GG + n)
                                  : (O1 + (size_t)m * GG + (n - GG));
            *(float4*)dst = v;
        }
    }
}

// ---------------------------------------------------------------------------
// word GEMM: 64x128 tile with the same register-prefetch pipeline
// ---------------------------------------------------------------------------
__global__ __launch_bounds__(256) void gemm64w(const float* __restrict__ A,
                                               const float* __restrict__ Wt,
                                               const float* __restrict__ bias,
                                               float* __restrict__ O0,
                                               float* __restrict__ O1) {
    __shared__ float As[16][68];
    __shared__ float Bs[16][132];
    const int tid = threadIdx.x;
    const int n0 = blockIdx.x * 128;
    const int m0 = blockIdx.y * 64;
    const int tn = tid & 15;
    const int tm = tid >> 4;
    const int r0 = tid >> 2, c4 = tid & 3;

    const float* ap = A + (size_t)(m0 + r0) * DD + c4 * 4;
    const float* w0p = Wt + (size_t)(n0 + r0) * DD + c4 * 4;
    const float* w1p = Wt + (size_t)(n0 + r0 + 64) * DD + c4 * 4;

    float acc[4][8];
#pragma unroll
    for (int y = 0; y < 4; ++y)
#pragma unroll
        for (int x = 0; x < 8; ++x) acc[y][x] = 0.f;

    float4 pa = *(const float4*)ap;
    float4 pw0 = *(const float4*)w0p;
    float4 pw1 = *(const float4*)w1p;

#pragma unroll 1
    for (int kt = 0; kt < 512; kt += 16) {
        As[c4 * 4 + 0][r0] = pa.x; As[c4 * 4 + 1][r0] = pa.y;
        As[c4 * 4 + 2][r0] = pa.z; As[c4 * 4 + 3][r0] = pa.w;
        Bs[c4 * 4 + 0][r0] = pw0.x; Bs[c4 * 4 + 1][r0] = pw0.y;
        Bs[c4 * 4 + 2][r0] = pw0.z; Bs[c4 * 4 + 3][r0] = pw0.w;
        Bs[c4 * 4 + 0][r0 + 64] = pw1.x; Bs[c4 * 4 + 1][r0 + 64] = pw1.y;
        Bs[c4 * 4 + 2][r0 + 64] = pw1.z; Bs[c4 * 4 + 3][r0 + 64] = pw1.w;
        __syncthreads();
        if (kt + 16 < 512) {
            pa = *(const float4*)(ap + kt + 16);
            pw0 = *(const float4*)(w0p + kt + 16);
            pw1 = *(const float4*)(w1p + kt + 16);
        }
#pragma unroll
        for (int k = 0; k < 16; ++k) {
            float4 a = *(const float4*)&As[k][tm * 4];
            float4 b0 = *(const float4*)&Bs[k][tn * 4];
            float4 b1 = *(const float4*)&Bs[k][64 + tn * 4];
            float av[4] = {a.x, a.y, a.z, a.w};
            float bv[8] = {b0.x, b0.y, b0.z, b0.w, b1.x, b1.y, b1.z, b1.w};
#pragma unroll
            for (int y = 0; y < 4; ++y)
#pragma unroll
                for (int x = 0; x < 8; ++x) acc[y][x] += av[y] * bv[x];
        }
        __syncthreads();
    }

#pragma unroll
    for (int y = 0; y < 4; ++y) {
        const int m = m0 + tm * 4 + y;
#pragma unroll
        for (int g = 0; g < 2; ++g) {
            int n = n0 + g * 64 + tn * 4;
            float4 v;
            v.x = acc[y][g * 4 + 0] + bias[n + 0];
            v.y = acc[y][g * 4 + 1] + bias[n + 1];
            v.z = acc[y][g * 4 + 2] + bias[n + 2];
            v.w = acc[y][g * 4 + 3] + bias[n + 3];
            float* dst = (n < DD) ? (O0 + (size_t)m * DD + n)
                                  : (O1 + (size_t)m * DD + (n - DD));
            *(float4*)dst = v;
        }
    }
}

// ---------------------------------------------------------------------------
// scorers / gate helpers
// ---------------------------------------------------------------------------
__device__ __forceinline__ float half_dot(const float* __restrict__ ar,
                                          const float* __restrict__ br,
                                          const float* __restrict__ cb,
                                          const float* __restrict__ cl,
                                          const float* __restrict__ cr,
                                          const float* __restrict__ q, int lane) {
    float part = 0.f;
#pragma unroll
    for (int d = lane; d < DD; d += 128) {
        float gi = ar[d] + br[d] + cb[d];
        float gfl = ar[DD + d] + br[DD + d] + cb[DD + d];
        float gfr = ar[2 * DD + d] + br[2 * DD + d] + cb[2 * DD + d];
        float gu = ar[3 * DD + d] + br[3 * DD + d] + cb[3 * DD + d];
        float go = ar[4 * DD + d] + br[4 * DD + d] + cb[4 * DD + d];
        float nc = cl[d] * sigm(gfl + 1.f) + cr[d] * sigm(gfr + 1.f) + tanhf(gu) * sigm(gi);
        part += sigm(go) * tanhf(nc) * q[d];
    }
#pragma unroll
    for (int off = 32; off; off >>= 1) part += __shfl_down(part, off);
    return part;
}

// plain-cached gate pair (cross-dispatch operands)
__device__ __forceinline__ void gate2n(const float* __restrict__ ar,
                                       const float* __restrict__ br,
                                       const float* __restrict__ cb,
                                       const float* __restrict__ cl,
                                       const float* __restrict__ cr, int d,
                                       float nh[2], float nc[2]) {
    float2 A0 = *(const float2*)(ar + d),          B0 = *(const float2*)(br + d);
    float2 A1 = *(const float2*)(ar + DD + d),     B1 = *(const float2*)(br + DD + d);
    float2 A2 = *(const float2*)(ar + 2 * DD + d), B2 = *(const float2*)(br + 2 * DD + d);
    float2 A3 = *(const float2*)(ar + 3 * DD + d), B3 = *(const float2*)(br + 3 * DD + d);
    float2 A4 = *(const float2*)(ar + 4 * DD + d), B4 = *(const float2*)(br + 4 * DD + d);
    float2 C0 = *(const float2*)(cb + d);
    float2 C1 = *(const float2*)(cb + DD + d);
    float2 C2 = *(const float2*)(cb + 2 * DD + d);
    float2 C3 = *(const float2*)(cb + 3 * DD + d);
    float2 C4 = *(const float2*)(cb + 4 * DD + d);
    float2 CL = *(const float2*)(cl + d);
    float2 CR = *(const float2*)(cr + d);
    float gi0 = A0.x + B0.x + C0.x, gi1 = A0.y + B0.y + C0.y;
    float gfl0 = A1.x + B1.x + C1.x, gfl1 = A1.y + B1.y + C1.y;
    float gfr0 = A2.x + B2.x + C2.x, gfr1 = A2.y + B2.y + C2.y;
    float gu0 = A3.x + B3.x + C3.x, gu1 = A3.y + B3.y + C3.y;
    float go0 = A4.x + B4.x + C4.x, go1 = A4.y + B4.y + C4.y;
    nc[0] = CL.x * sigm(gfl0 + 1.f) + CR.x * sigm(gfr0 + 1.f) + tanhf(gu0) * sigm(gi0);
    nc[1] = CL.y * sigm(gfl1 + 1.f) + CR.y * sigm(gfr1 + 1.f) + tanhf(gu1) * sigm(gi1);
    nh[0] = sigm(go0) * tanhf(nc[0]);
    nh[1] = sigm(go1) * tanhf(nc[1]);
}

// sc1 gate pair (a/b rows may be written by same-dispatch B blocks)
__device__ __forceinline__ void gate2c(const float* ar, const float* br,
                                       const float* __restrict__ cb,
                                       const float* __restrict__ cl,
                                       const float* __restrict__ cr, int d,
                                       float nh[2], float nc[2]) {
    float2 A0 = ldf2(ar + d),          B0 = ldf2(br + d);
    float2 A1 = ldf2(ar + DD + d),     B1 = ldf2(br + DD + d);
    float2 A2 = ldf2(ar + 2 * DD + d), B2 = ldf2(br + 2 * DD + d);
    float2 A3 = ldf2(ar + 3 * DD + d), B3 = ldf2(br + 3 * DD + d);
    float2 A4 = ldf2(ar + 4 * DD + d), B4 = ldf2(br + 4 * DD + d);
    float2 C0 = *(const float2*)(cb + d);
    float2 C1 = *(const float2*)(cb + DD + d);
    float2 C2 = *(const float2*)(cb + 2 * DD + d);
    float2 C3 = *(const float2*)(cb + 3 * DD + d);
    float2 C4 = *(const float2*)(cb + 4 * DD + d);
    float2 CL = *(const float2*)(cl + d);
    float2 CR = *(const float2*)(cr + d);
    float gi0 = A0.x + B0.x + C0.x, gi1 = A0.y + B0.y + C0.y;
    float gfl0 = A1.x + B1.x + C1.x, gfl1 = A1.y + B1.y + C1.y;
    float gfr0 = A2.x + B2.x + C2.x, gfr1 = A2.y + B2.y + C2.y;
    float gu0 = A3.x + B3.x + C3.x, gu1 = A3.y + B3.y + C3.y;
    float go0 = A4.x + B4.x + C4.x, go1 = A4.y + B4.y + C4.y;
    nc[0] = CL.x * sigm(gfl0 + 1.f) + CR.x * sigm(gfr0 + 1.f) + tanhf(gu0) * sigm(gi0);
    nc[1] = CL.y * sigm(gfl1 + 1.f) + CR.y * sigm(gfr1 + 1.f) + tanhf(gu1) * sigm(gi1);
    nh[0] = sigm(go0) * tanhf(nc[0]);
    nh[1] = sigm(go1) * tanhf(nc[1]);
}

// ---------------------------------------------------------------------------
// initial scores: grid (12, 64)
// ---------------------------------------------------------------------------
__global__ __launch_bounds__(256) void scoreall_k(const float* __restrict__ acache,
                                                  const float* __restrict__ bcache,
                                                  const float* __restrict__ cbuf,
                                                  const float* __restrict__ compb,
                                                  const float* __restrict__ q,
                                                  float* __restrict__ scores_g) {
    __shared__ float red_s[4];
    const int tid = threadIdx.x;
    const int b = blockIdx.y;
    const int p = blockIdx.x * 2 + (tid >> 7);
    const bool valid = p < NSTEP;
    float w = 0.f;
    if (valid) {
        w = half_dot(acache + (size_t)(b * LL + p) * GG,
                     bcache + (size_t)(b * LL + p + 1) * GG, compb,
                     cbuf + (size_t)(b * LL + p) * DD,
                     cbuf + (size_t)(b * LL + p + 1) * DD, q, tid & 127);
    }
    if ((tid & 63) == 0) red_s[tid >> 6] = w;
    __syncthreads();
    if ((tid == 0 || tid == 128) && valid) {
        int base = tid >> 6;
        scores_g[b * NSTEP + p] = red_s[base] + red_s[base + 1];
    }
}

// ---------------------------------------------------------------------------
// stepA device body (templated on coherent gate loads). i==0 path plain.
// ---------------------------------------------------------------------------
template <bool COH>
__device__ void stepA_body(int i, const int* __restrict__ length, float* __restrict__ cbuf,
                           const float* __restrict__ acache, const float* __restrict__ bcache,
                           float* __restrict__ hout, float* __restrict__ scores_g,
                           int* __restrict__ seq_g, int* __restrict__ kp_g,
                           int* __restrict__ msel, const float* __restrict__ compb,
                           const float* __restrict__ q, float* __restrict__ out, int b,
                           float* red_s, float* sc_l, int* seq_l, int* k_sh) {
    const int tid = threadIdx.x;
    const int lane7 = tid & 127;
    const int lenb = length[b];
    const int ncand = NSTEP - i;

    if (i == 0) {
        if (tid < LL) seq_l[tid] = tid;
    } else {
        if (tid < LL - i) seq_l[tid] = seq_g[b * 32 + tid];
    }
    if (tid < ncand) sc_l[tid] = scores_g[b * NSTEP + tid];
    __syncthreads();
    const int kp = (i > 0) ? kp_g[b] : 0;

    if (i > 0 && i < lenb) {
        int p = (tid < 128) ? (kp - 1) : kp;
        bool valid = (p >= 0) && (p < ncand);
        float w = 0.f;
        if (valid) {
            int sl = seq_l[p], sr = seq_l[p + 1];
            const float* ar = acache + (size_t)(b * LL + sl) * GG;
            const float* br = bcache + (size_t)(b * LL + sr) * GG;
            const float* cl = cbuf + (size_t)(b * LL + sl) * DD;
            const float* cr = cbuf + (size_t)(b * LL + sr) * DD;
#pragma unroll
            for (int pass = 0; pass < 2; ++pass) {
                int d = pass * 256 + lane7 * 2;
                float nh[2], nc[2];
                if (COH) gate2c(ar, br, compb, cl, cr, d, nh, nc);
                else gate2n(ar, br, compb, cl, cr, d, nh, nc);
                float2 Q = *(const float2*)(q + d);
                w += nh[0] * Q.x + nh[1] * Q.y;
            }
#pragma unroll
            for (int off = 32; off; off >>= 1) w += __shfl_down(w, off);
        }
        if ((tid & 63) == 0) red_s[tid >> 6] = w;
        __syncthreads();
        if (tid == 0) {
            if (kp - 1 >= 0) sc_l[kp - 1] = red_s[0] + red_s[1];
            if (kp < ncand) sc_l[kp] = red_s[2] + red_s[3];
        }
        __syncthreads();
    }

    if (i + 1 < lenb) {
        if (tid == 0) {
            const int vmax = lenb - i - 2;
            int k = 0;
            float best = sc_l[0];
            for (int pp = 1; pp <= vmax; ++pp)
                if (sc_l[pp] > best) { best = sc_l[pp]; k = pp; }
            *k_sh = k;
        }
        __syncthreads();
        const int k = *k_sh;
        const int sl = seq_l[k], sr = seq_l[k + 1];
        const float* ar = acache + (size_t)(b * LL + sl) * GG;
        const float* br = bcache + (size_t)(b * LL + sr) * GG;
        const float* cl = cbuf + (size_t)(b * LL + sl) * DD;
        const float* cr = cbuf + (size_t)(b * LL + sr) * DD;
        {
            const int d = 2 * tid;
            float nh[2], nc[2];
            if (COH) gate2c(ar, br, compb, cl, cr, d, nh, nc);
            else gate2n(ar, br, compb, cl, cr, d, nh, nc);
            *(float2*)(cbuf + (size_t)(b * LL + sl) * DD + d) = make_float2(nc[0], nc[1]);
            *(float2*)(hout + (size_t)b * DD + d) = make_float2(nh[0], nh[1]);
            if (i == NSTEP - 1)
                *(float2*)(out + (size_t)b * DD + d) = make_float2(nh[0], nh[1]);
        }
        float sv = (tid + 1 < ncand) ? sc_l[tid + 1] : 0.f;
        int qv = (tid + 1 < LL - i) ? seq_l[tid + 1] : 0;
        __syncthreads();
        if (tid >= k + 1 && tid <= ncand - 2) sc_l[tid] = sv;
        if (tid >= k + 1 && tid <= LL - i - 2) seq_l[tid] = qv;
        if (tid < ncand - 1) scores_g[b * NSTEP + tid] = sc_l[tid];
        if (tid < LL - i - 1) seq_g[b * 32 + tid] = seq_l[tid];
        if (tid == 0) { kp_g[b] = k; msel[b] = sl; }
    } else if (i == NSTEP - 1) {
        const int d = 2 * tid;
        *(float2*)(out + (size_t)b * DD + d) = *(const float2*)(hout + (size_t)b * DD + d);
    }
}

// stepA(0): plain 64-block dispatch
__global__ __launch_bounds__(256) void stepA0_k(
    const int* __restrict__ length, float* __restrict__ cbuf,
    const float* __restrict__ acache, const float* __restrict__ bcache,
    float* __restrict__ hout, float* __restrict__ scores_g, int* __restrict__ seq_g,
    int* __restrict__ kp_g, int* __restrict__ msel, const float* __restrict__ compb,
    const float* __restrict__ q, float* __restrict__ out) {
    __shared__ float red_s[4];
    __shared__ float sc_l[32];
    __shared__ int seq_l[32];
    __shared__ int k_sh;
    stepA_body<false>(0, length, cbuf, (const float*)acache, (const float*)bcache, hout,
                      scores_g, seq_g, kp_g, msel, compb, q, out, blockIdx.x, red_s, sc_l,
                      seq_l, &k_sh);
}

// ---------------------------------------------------------------------------
// fused dispatch i (i=1..22): blocks 64..223 run stepB(i-1) (a/b rows of the
// item merged at step i-1, sc1 stores, arrive on counters); blocks 0..63 wait
// for all 160 arrivals, then run stepA(i) with sc1 gate loads.
// ---------------------------------------------------------------------------
__global__ __launch_bounds__(256) void fusedBA_k(
    int i, const int* __restrict__ length, float* __restrict__ cbuf,
    float* __restrict__ acache, float* __restrict__ bcache, float* __restrict__ hout,
    float* __restrict__ scores_g, int* __restrict__ seq_g, int* __restrict__ kp_g,
    int* __restrict__ msel, const float* __restrict__ comp_W,
    const float* __restrict__ compb, const float* __restrict__ q, float* __restrict__ out,
    int* __restrict__ bar) {
    __shared__ float As[128][68];
    __shared__ float Bs[128][36];
    __shared__ int msel_s[BB];
    __shared__ float red_s[4];
    __shared__ float sc_l[32];
    __shared__ int seq_l[32];
    __shared__ int k_sh;

    const int tid = threadIdx.x;
    const int bid = blockIdx.x;
    int* lines = bar + i * 64;  // 4 padded counter lines for this step

    if (bid >= BB) {
        // ---------------- stepB(i-1): tile (bid-64) of 160 ----------------
        const int t = bid - BB;
        const int sar = tid & 63, sak = tid >> 6;
        const int swn = tid & 31, swk = tid >> 5;
        const int tn = tid & 15, tm = tid >> 4;
        if (tid < BB) msel_s[tid] = msel[tid];
        int n = t * 32 + swn;
        const float* wrow = (n < GG) ? (comp_W + (size_t)n * (2 * DD))
                                     : (comp_W + (size_t)(n - GG) * (2 * DD) + DD);
        const float* arow = hout + (size_t)sar * DD;
        float acc[4][2];
#pragma unroll
        for (int y = 0; y < 4; ++y) { acc[y][0] = 0.f; acc[y][1] = 0.f; }
        float4 ra[8], rw[4];
#pragma unroll
        for (int j = 0; j < 8; ++j) ra[j] = *(const float4*)(arow + sak * 32 + j * 4);
#pragma unroll
        for (int j = 0; j < 4; ++j) rw[j] = *(const float4*)(wrow + swk * 16 + j * 4);
#pragma unroll 1
        for (int c = 0; c < 4; ++c) {
            __syncthreads();
#pragma unroll
            for (int j = 0; j < 8; ++j) {
                int kl = sak * 32 + j * 4;
                As[kl + 0][sar] = ra[j].x;
                As[kl + 1][sar] = ra[j].y;
                As[kl + 2][sar] = ra[j].z;
                As[kl + 3][sar] = ra[j].w;
            }
#pragma unroll
            for (int j = 0; j < 4; ++j) {
                int kl = swk * 16 + j * 4;
                Bs[kl + 0][swn] = rw[j].x;
                Bs[kl + 1][swn] = rw[j].y;
                Bs[kl + 2][swn] = rw[j].z;
                Bs[kl + 3][swn] = rw[j].w;
            }
            if (c < 3) {
                int kb = (c + 1) * 128;
#pragma unroll
                for (int j = 0; j < 8; ++j)
                    ra[j] = *(const float4*)(arow + kb + sak * 32 + j * 4);
#pragma unroll
                for (int j = 0; j < 4; ++j)
                    rw[j] = *(const float4*)(wrow + kb + swk * 16 + j * 4);
            }
            __syncthreads();
#pragma unroll 8
            for (int k = 0; k < 128; ++k) {
                float4 a = *(const float4*)&As[k][tm * 4];
                float2 w = *(const float2*)&Bs[k][tn * 2];
                acc[0][0] += a.x * w.x; acc[0][1] += a.x * w.y;
                acc[1][0] += a.y * w.x; acc[1][1] += a.y * w.y;
                acc[2][0] += a.z * w.x; acc[2][1] += a.z * w.y;
                acc[3][0] += a.w * w.x; acc[3][1] += a.w * w.y;
            }
        }
        const int n0 = t * 32 + tn * 2;
#pragma unroll
        for (int y = 0; y < 4; ++y) {
            int m = tm * 4 + y;
            size_t row = (size_t)(m * LL + msel_s[m]);
            float* dst = (n0 < GG) ? (acache + row * GG + n0)
                                   : (bcache + row * GG + (n0 - GG));
            stf2(dst, acc[y][0], acc[y][1]);  // sc1: read by A-blocks this dispatch
        }
        __syncthreads();
        if (tid == 0) {
            drain_stores();
            (void)__hip_atomic_fetch_add(lines + (bid & 3) * 16, 1, __ATOMIC_RELAXED,
                                         __HIP_MEMORY_SCOPE_AGENT);
        }
    } else {
        // ---------------- stepA(i): batch = bid ----------------
        const int b = bid;
        if (i < length[b]) {  // need this step's B output: wait for 160 arrivals
            if (tid < 64) {
                for (;;) {
                    int v = (tid < 4) ? ldi(lines + tid * 16) : 40;
                    if (__all(v >= 40)) break;
                    __builtin_amdgcn_s_sleep(8);
                }
            }
            __syncthreads();
        }
        stepA_body<true>(i, length, cbuf, acache, bcache, hout, scores_g, seq_g, kp_g,
                         msel, compb, q, out, b, red_s, sc_l, seq_l, &k_sh);
    }
}

// ---------------------------------------------------------------------------
extern "C" void kernel_launch(void* const* d_in, const int* in_sizes, int n_in, void* d_out,
                              int out_size, void* d_ws, size_t ws_size, hipStream_t stream) {
    const float* inp = (const float*)d_in[0];
    const int* length = (const int*)d_in[1];
    const float* word_W = (const float*)d_in[2];
    const float* word_b = (const float*)d_in[3];
    const float* comp_W = (const float*)d_in[4];
    const float* comp_b = (const float*)d_in[5];
    const float* comp_q = (const float*)d_in[6];
    float* out = (float*)d_out;

    float* ws = (float*)d_ws;
    size_t off = 0;
    float* hbuf = ws + off;   off += (size_t)BB * LL * DD;
    float* cbuf = ws + off;   off += (size_t)BB * LL * DD;
    float* acache = ws + off; off += (size_t)BB * LL * GG;
    float* bcache = ws + off; off += (size_t)BB * LL * GG;
    float* hout = ws + off;   off += (size_t)BB * DD;
    float* scores = ws + off; off += 2048;
    int* seq_g = (int*)(ws + off); off += BB * 32;
    int* kp_g = (int*)(ws + off);  off += 64;
    int* msel = (int*)(ws + off);  off += 64;
    int* bar = (int*)(ws + off);   off += NSTEP * 64;
    (void)ws_size; (void)in_sizes; (void)n_in; (void)out_size;

    init_k<<<1, 256, 0, stream>>>(bar);

    // word projection
    gemm64w<<<dim3(8, 24), 256, 0, stream>>>(inp, word_W, word_b, hbuf, cbuf);

    // a/b caches for all 1536 items
    gemm_big<<<dim3(40, 12), 256, 0, stream>>>(hbuf, comp_W, acache, bcache);

    // initial candidate scores
    scoreall_k<<<dim3(12, 64), 256, 0, stream>>>(acache, bcache, cbuf, comp_b, comp_q, scores);

    // step 0: select+merge only
    stepA0_k<<<BB, 256, 0, stream>>>(length, cbuf, acache, bcache, hout, scores, seq_g,
                                     kp_g, msel, comp_b, comp_q, out);

    // steps 1..22: fused stepB(i-1) + stepA(i), one cooperative dispatch each
    for (int i = 1; i < NSTEP; ++i) {
        int ia = i;
        const int* a0 = length;
        float* a1 = cbuf; float* a2 = acache; float* a3 = bcache; float* a4 = hout;
        float* a5 = scores; int* a6 = seq_g; int* a7 = kp_g; int* a8 = msel;
        const float* a9 = comp_W; const float* a10 = comp_b; const float* a11 = comp_q;
        float* a12 = out; int* a13 = bar;
        void* args[] = {&ia, &a0, &a1, &a2, &a3, &a4, &a5, &a6, &a7, &a8,
                        &a9, &a10, &a11, &a12, &a13};
        hipError_t err = hipLaunchCooperativeKernel(reinterpret_cast<void*>(fusedBA_k),
                                                    dim3(FUSED_BLOCKS), dim3(256), args, 0,
                                                    stream);
        (void)err;
    }
}